// Round 1
// baseline (27.524 us; speedup 1.0000x reference)
//
#include <hip/hip_runtime.h>

// BSpline3D: out[b,c,d,h,w] = sum_k relu(x[b,c,d,h,w] - knots[k])^3 * weights[c,k]
// x: (2, 32, 64, 64, 64) f32, knots: (10,) f32, weights: (32, 10) f32.
// Memory-bound elementwise op: 64 MiB in + 64 MiB out, ~50 flops/elem.

#define NK 10
// 64^3 = 262144 elements per channel; /4 per float4 vector -> 65536 = 2^16
#define CH_SHIFT 16
#define CH_MASK 31

__global__ __launch_bounds__(256) void bspline3d_kernel(
    const float* __restrict__ x,
    const float* __restrict__ knots,
    const float* __restrict__ weights,
    float* __restrict__ out,
    int nvec)
{
    // Knots are tiny and uniform: hoist into registers once.
    float kn[NK];
#pragma unroll
    for (int k = 0; k < NK; ++k) kn[k] = knots[k];

    const int stride = gridDim.x * blockDim.x;
    for (int v = blockIdx.x * blockDim.x + threadIdx.x; v < nvec; v += stride) {
        const int c = (v >> CH_SHIFT) & CH_MASK;          // wave-uniform
        const float* __restrict__ wc = weights + c * NK;  // broadcasts from L1

        const float4 xv = reinterpret_cast<const float4*>(x)[v];

        float a0 = 0.f, a1 = 0.f, a2 = 0.f, a3 = 0.f;
#pragma unroll
        for (int k = 0; k < NK; ++k) {
            const float kk = kn[k];
            const float w  = wc[k];
            float b0 = fmaxf(xv.x - kk, 0.f);
            float b1 = fmaxf(xv.y - kk, 0.f);
            float b2 = fmaxf(xv.z - kk, 0.f);
            float b3 = fmaxf(xv.w - kk, 0.f);
            a0 = fmaf((b0 * b0) * b0, w, a0);
            a1 = fmaf((b1 * b1) * b1, w, a1);
            a2 = fmaf((b2 * b2) * b2, w, a2);
            a3 = fmaf((b3 * b3) * b3, w, a3);
        }
        reinterpret_cast<float4*>(out)[v] = make_float4(a0, a1, a2, a3);
    }
}

extern "C" void kernel_launch(void* const* d_in, const int* in_sizes, int n_in,
                              void* d_out, int out_size, void* d_ws, size_t ws_size,
                              hipStream_t stream) {
    const float* x       = (const float*)d_in[0];
    const float* knots   = (const float*)d_in[1];
    const float* weights = (const float*)d_in[2];
    float* out           = (float*)d_out;

    const int nvec = out_size / 4;  // 16,777,216 / 4 = 4,194,304 float4s
    const int block = 256;
    int grid = (nvec + block - 1) / block;
    if (grid > 2048) grid = 2048;   // grid-stride: 256 CU x 8 blocks

    bspline3d_kernel<<<grid, block, 0, stream>>>(x, knots, weights, out, nvec);
}

// Round 2
// 26.392 us; speedup vs baseline: 1.0429x; 1.0429x over previous
//
#include <hip/hip_runtime.h>

// BSpline3D: out[b,c,d,h,w] = sum_k relu(x[b,c,d,h,w] - knots[k])^3 * weights[c,k]
// x: (2, 32, 64, 64, 64) f32, knots: (10,) f32, weights: (32, 10) f32.
// Memory-bound: 64 MiB in + 64 MiB out. Strategy: one channel-chunk per block
// group so weights are hoisted to registers; inner loop is pure stream.

#define NK 10
#define VECS_PER_CHUNK 65536   // 64^3 / 4 float4s per (b,c) chunk
#define BLOCKS_PER_CHUNK 32
#define VECS_PER_BLOCK 2048    // VECS_PER_CHUNK / BLOCKS_PER_CHUNK
#define ITERS 8                // VECS_PER_BLOCK / 256 threads

__global__ __launch_bounds__(256) void bspline3d_kernel(
    const float* __restrict__ x,
    const float* __restrict__ knots,
    const float* __restrict__ weights,
    float* __restrict__ out)
{
    const int blk   = blockIdx.x;
    const int chunk = blk >> 5;        // 0..63 : linear (b, c) chunk index
    const int sub   = blk & 31;        // 0..31 : sub-block within the chunk
    const int c     = chunk & 31;      // channel — uniform across the block

    // Hoist knots and this channel's weights into registers (block-uniform).
    float kn[NK], w[NK];
    const float* __restrict__ wc = weights + c * NK;
#pragma unroll
    for (int k = 0; k < NK; ++k) { kn[k] = knots[k]; w[k] = wc[k]; }

    const long base = (long)chunk * VECS_PER_CHUNK + (long)sub * VECS_PER_BLOCK;
    const float4* __restrict__ xv4 = reinterpret_cast<const float4*>(x) + base;
    float4* __restrict__ ov4       = reinterpret_cast<float4*>(out) + base;

#pragma unroll 2
    for (int i = 0; i < ITERS; ++i) {
        const int idx = i * 256 + (int)threadIdx.x;   // coalesced
        const float4 xv = xv4[idx];

        float a0 = 0.f, a1 = 0.f, a2 = 0.f, a3 = 0.f;
#pragma unroll
        for (int k = 0; k < NK; ++k) {
            const float kk = kn[k];
            const float wk = w[k];
            float b0 = fmaxf(xv.x - kk, 0.f);
            float b1 = fmaxf(xv.y - kk, 0.f);
            float b2 = fmaxf(xv.z - kk, 0.f);
            float b3 = fmaxf(xv.w - kk, 0.f);
            a0 = fmaf((b0 * b0) * b0, wk, a0);
            a1 = fmaf((b1 * b1) * b1, wk, a1);
            a2 = fmaf((b2 * b2) * b2, wk, a2);
            a3 = fmaf((b3 * b3) * b3, wk, a3);
        }
        ov4[idx] = make_float4(a0, a1, a2, a3);
    }
}

extern "C" void kernel_launch(void* const* d_in, const int* in_sizes, int n_in,
                              void* d_out, int out_size, void* d_ws, size_t ws_size,
                              hipStream_t stream) {
    const float* x       = (const float*)d_in[0];
    const float* knots   = (const float*)d_in[1];
    const float* weights = (const float*)d_in[2];
    float* out           = (float*)d_out;

    // out_size = 2*32*64^3 = 16,777,216 floats -> 64 chunks of 65536 float4s.
    const int nchunks = (out_size / 4) / VECS_PER_CHUNK;   // 64
    const int grid = nchunks * BLOCKS_PER_CHUNK;           // 2048

    bspline3d_kernel<<<grid, 256, 0, stream>>>(x, knots, weights, out);
}